// Round 4
// baseline (283.051 us; speedup 1.0000x reference)
//
#include <hip/hip_runtime.h>
#include <float.h>
#include <math.h>

#define BATCH 8
#define NPTS 4096
#define KNN 10
#define BN (BATCH * NPTS)
#define QPB 32                 // queries per block
#define SEGS 8                 // scan segments (threads per query)
#define QUARTER 1024           // points staged per pass (16 KiB as float4)
#define SEGC (QUARTER / SEGS)  // 128 candidates per thread per pass
#define GRIDX (NPTS / QPB)     // 128
#define TOTAL_BLOCKS (GRIDX * BATCH * 2)  // 2048

__device__ inline float med3f(float x, float a, float b) {
    return __builtin_amdgcn_fmed3f(x, a, b);
}

// Eigenvector of smallest eigenvalue of symmetric 3x3
__device__ inline void smallest_eigvec(float a00, float a01, float a02,
                                       float a11, float a12, float a22,
                                       float& vx, float& vy, float& vz) {
    float p1 = a01 * a01 + a02 * a02 + a12 * a12;
    float q = (a00 + a11 + a22) * (1.0f / 3.0f);
    float b00 = a00 - q, b11 = a11 - q, b22 = a22 - q;
    float p2 = b00 * b00 + b11 * b11 + b22 * b22 + 2.0f * p1;
    float p = sqrtf(p2 * (1.0f / 6.0f));
    if (p < 1e-20f) { vx = 1.0f; vy = 0.0f; vz = 0.0f; return; }
    float ip = 1.0f / p;
    float c00 = b00 * ip, c01 = a01 * ip, c02 = a02 * ip;
    float c11 = b11 * ip, c12 = a12 * ip, c22 = b22 * ip;
    float detB = c00 * (c11 * c22 - c12 * c12)
               - c01 * (c01 * c22 - c12 * c02)
               + c02 * (c01 * c12 - c11 * c02);
    float r = 0.5f * detB;
    r = fminf(1.0f, fmaxf(-1.0f, r));
    float phi = acosf(r) * (1.0f / 3.0f);
    float lmin = q + 2.0f * p * cosf(phi + 2.0943951023931953f);

    float m00 = a00 - lmin, m11 = a11 - lmin, m22 = a22 - lmin;
    float r0x = m00, r0y = a01, r0z = a02;
    float r1x = a01, r1y = m11, r1z = a12;
    float r2x = a02, r2y = a12, r2z = m22;
    float c0x = r0y * r1z - r0z * r1y, c0y = r0z * r1x - r0x * r1z, c0z = r0x * r1y - r0y * r1x;
    float c1x = r0y * r2z - r0z * r2y, c1y = r0z * r2x - r0x * r2z, c1z = r0x * r2y - r0y * r2x;
    float c2x = r1y * r2z - r1z * r2y, c2y = r1z * r2x - r1x * r2z, c2z = r1x * r2y - r1y * r2x;
    float n0 = c0x * c0x + c0y * c0y + c0z * c0z;
    float n1 = c1x * c1x + c1y * c1y + c1z * c1z;
    float n2 = c2x * c2x + c2y * c2y + c2z * c2z;
    float bx = c0x, by = c0y, bz = c0z, bnm = n0;
    if (n1 > bnm) { bx = c1x; by = c1y; bz = c1z; bnm = n1; }
    if (n2 > bnm) { bx = c2x; by = c2y; bz = c2z; bnm = n2; }
    if (bnm < 1e-30f) { vx = 1.0f; vy = 0.0f; vz = 0.0f; return; }
    float inv = rsqrtf(bnm);
    vx = bx * inv; vy = by * inv; vz = bz * inv;
}

__global__ void init_counter_kernel(unsigned* __restrict__ counter) {
    if (threadIdx.x == 0) *counter = 0u;
}

// 256 threads = 32 queries x 8 segments. Cloud staged in four 16 KiB quarter
// passes -> ~17 KiB LDS -> 8 blocks/CU (32 waves/CU). Last-finishing block
// reduces the loss (threadfence + device-scope atomic counter).
__global__ __launch_bounds__(256, 8) void knn_normals_fused(
    const float* __restrict__ pred, const float* __restrict__ gt,
    float* __restrict__ normals /* [2][3][BN] */, unsigned* __restrict__ counter,
    float* __restrict__ out) {
    __shared__ float4 pts[QUARTER];   // 16 KiB; reused as merge keybuf
    __shared__ float red[256];
    __shared__ int islast;

    const int b = blockIdx.y;
    const int cloud = blockIdx.z;
    const float* __restrict__ base = (cloud == 0 ? pred : gt) + b * 3 * NPTS;
    const int tid = threadIdx.x;
    const int lp = tid & (QPB - 1);
    const int seg = tid >> 5;
    const int pt = blockIdx.x * QPB + lp;

    const float mex = base[pt];
    const float mey = base[NPTS + pt];
    const float mez = base[2 * NPTS + pt];
    const float nmx = -2.0f * mex, nmy = -2.0f * mey, nmz = -2.0f * mez;

    float k[KNN];
#pragma unroll
    for (int j = 0; j < KNN; ++j) k[j] = FLT_MAX;

    for (int pass = 0; pass < 4; ++pass) {
        const int pb = pass * QUARTER;
#pragma unroll
        for (int i = tid; i < QUARTER; i += 256) {
            float x = base[pb + i];
            float y = base[NPTS + pb + i];
            float z = base[2 * NPTS + pb + i];
            pts[i] = make_float4(x, y, z, fmaf(x, x, fmaf(y, y, z * z)));
        }
        __syncthreads();

        const int s0 = seg * SEGC;
        const unsigned gb = (unsigned)(pb + s0);
#pragma unroll 8
        for (int c = 0; c < SEGC; ++c) {
            float4 p = pts[s0 + c];
            // d' = |p|^2 - 2 p.me  (squared distance shifted by -|me|^2: per-query
            // constant shift, ordering-preserving)
            float d = fmaf(p.z, nmz, fmaf(p.y, nmy, fmaf(p.x, nmx, p.w)));
            float key = __uint_as_float((__float_as_uint(d) & 0xFFFFF000u) | (gb + c));
#pragma unroll
            for (int j = KNN - 1; j >= 1; --j) k[j] = med3f(key, k[j - 1], k[j]);
            k[0] = fminf(key, k[0]);
        }
        __syncthreads();   // scan done before restage / keybuf reuse
    }

    float* keybuf = (float*)pts;   // alias: scans complete, stage dead
    if (seg != 0) {
#pragma unroll
        for (int j = 0; j < KNN; ++j) keybuf[((seg - 1) * QPB + lp) * KNN + j] = k[j];
    }
    __syncthreads();

    if (seg == 0) {
        for (int s = 0; s < SEGS - 1; ++s) {
#pragma unroll
            for (int jj = 0; jj < KNN; ++jj) {
                float key = keybuf[(s * QPB + lp) * KNN + jj];
#pragma unroll
                for (int j = KNN - 1; j >= 1; --j) k[j] = med3f(key, k[j - 1], k[j]);
                k[0] = fminf(key, k[0]);
            }
        }

        // raw-moment covariance (no neighbor arrays -> low VGPR)
        float sx = 0.f, sy = 0.f, sz = 0.f;
        float sxx = 0.f, sxy = 0.f, sxz = 0.f, syy = 0.f, syz = 0.f, szz = 0.f;
#pragma unroll
        for (int j = 0; j < KNN; ++j) {
            int idx = (int)(__float_as_uint(k[j]) & 0xFFFu);
            float x = base[idx], y = base[NPTS + idx], z = base[2 * NPTS + idx];
            sx += x; sy += y; sz += z;
            sxx = fmaf(x, x, sxx); sxy = fmaf(x, y, sxy); sxz = fmaf(x, z, sxz);
            syy = fmaf(y, y, syy); syz = fmaf(y, z, syz); szz = fmaf(z, z, szz);
        }
        const float iK = 1.0f / KNN;
        float mx = sx * iK, my = sy * iK, mz = sz * iK;
        float cxx = sxx * iK - mx * mx, cxy = sxy * iK - mx * my, cxz = sxz * iK - mx * mz;
        float cyy = syy * iK - my * my, cyz = syz * iK - my * mz, czz = szz * iK - mz * mz;

        float vx, vy, vz;
        smallest_eigvec(cxx, cxy, cxz, cyy, cyz, czz, vx, vy, vz);

        float* outp = normals + cloud * 3 * BN;
        const int oidx = b * NPTS + pt;
        outp[oidx] = vx;
        outp[BN + oidx] = vy;
        outp[2 * BN + oidx] = vz;
    }

    // completion protocol: make normals visible device-wide, then count
    __threadfence();
    __syncthreads();
    if (tid == 0) {
        unsigned old = atomicAdd(counter, 1u);
        islast = (old == TOTAL_BLOCKS - 1) ? 1 : 0;
    }
    __syncthreads();

    if (islast) {
        __threadfence();   // acquire: order our reads after counter observation
        const float* pn = normals;
        const float* gn = normals + 3 * BN;
        float acc = 0.f;
        for (int i = tid; i < BN; i += 256) {
            float px = pn[i], py = pn[BN + i], pz = pn[2 * BN + i];
            float gx = gn[i], gy = gn[BN + i], gz = gn[2 * BN + i];
            float dot = px * gx + py * gy + pz * gz;
            float npn = sqrtf(px * px + py * py + pz * pz);
            float ngn = sqrtf(gx * gx + gy * gy + gz * gz);
            float denom = fmaxf(npn * ngn, 1e-8f);
            acc += 1.0f - fabsf(dot / denom);
        }
        red[tid] = acc;
        __syncthreads();
        for (int s = 128; s > 0; s >>= 1) {
            if (tid < s) red[tid] += red[tid + s];
            __syncthreads();
        }
        if (tid == 0) out[0] = red[0] * (1.0f / BN);
    }
}

extern "C" void kernel_launch(void* const* d_in, const int* in_sizes, int n_in,
                              void* d_out, int out_size, void* d_ws, size_t ws_size,
                              hipStream_t stream) {
    const float* pred = (const float*)d_in[0];
    const float* gt = (const float*)d_in[1];
    float* out = (float*)d_out;
    unsigned* counter = (unsigned*)d_ws;           // 1 u32 (16 B slot for alignment)
    float* normals = (float*)d_ws + 4;             // 6*BN floats = 786 KiB

    init_counter_kernel<<<1, 64, 0, stream>>>(counter);
    dim3 grid(GRIDX, BATCH, 2);                    // 128 x 8 x 2 = 2048 blocks
    knn_normals_fused<<<grid, 256, 0, stream>>>(pred, gt, normals, counter, out);
}

// Round 5
// 234.131 us; speedup vs baseline: 1.2089x; 1.2089x over previous
//
#include <hip/hip_runtime.h>
#include <float.h>
#include <math.h>

#define BATCH 8
#define NPTS 4096
#define KNN 10
#define BN (BATCH * NPTS)          // 32768 points per cloud
#define TPB 512                    // threads per block = 8 waves
#define WAVES 8                    // scan segments, one per wave (wave-uniform LDS reads)
#define QPB 128                    // queries per block = 64 lanes x Q=2
#define HALF 2048                  // points staged per pass (32 KiB as float4)
#define SEGC (HALF / WAVES)        // 256 candidates per wave per pass
#define GRIDX (NPTS / QPB)         // 32
#define TOTAL_BLOCKS (GRIDX * BATCH * 2)  // 512
#define KB_STRIDE (2 * KNN + 1)    // 21: merge keybuf stride, odd -> no bank conflicts

__device__ inline float med3f(float x, float a, float b) {
    return __builtin_amdgcn_fmed3f(x, a, b);
}

// branchless sorted insert of key into ascending k[0..9] (drop largest)
#define INSERT(karr, key)                                              \
    do {                                                               \
        _Pragma("unroll")                                              \
        for (int _j = KNN - 1; _j >= 1; --_j)                          \
            karr[_j] = med3f((key), karr[_j - 1], karr[_j]);           \
        karr[0] = fminf((key), karr[0]);                               \
    } while (0)

// Eigenvector of smallest eigenvalue of symmetric 3x3
__device__ inline void smallest_eigvec(float a00, float a01, float a02,
                                       float a11, float a12, float a22,
                                       float& vx, float& vy, float& vz) {
    float p1 = a01 * a01 + a02 * a02 + a12 * a12;
    float q = (a00 + a11 + a22) * (1.0f / 3.0f);
    float b00 = a00 - q, b11 = a11 - q, b22 = a22 - q;
    float p2 = b00 * b00 + b11 * b11 + b22 * b22 + 2.0f * p1;
    float p = sqrtf(p2 * (1.0f / 6.0f));
    if (p < 1e-20f) { vx = 1.0f; vy = 0.0f; vz = 0.0f; return; }
    float ip = 1.0f / p;
    float c00 = b00 * ip, c01 = a01 * ip, c02 = a02 * ip;
    float c11 = b11 * ip, c12 = a12 * ip, c22 = b22 * ip;
    float detB = c00 * (c11 * c22 - c12 * c12)
               - c01 * (c01 * c22 - c12 * c02)
               + c02 * (c01 * c12 - c11 * c02);
    float r = 0.5f * detB;
    r = fminf(1.0f, fmaxf(-1.0f, r));
    float phi = acosf(r) * (1.0f / 3.0f);
    float lmin = q + 2.0f * p * cosf(phi + 2.0943951023931953f);

    float m00 = a00 - lmin, m11 = a11 - lmin, m22 = a22 - lmin;
    float r0x = m00, r0y = a01, r0z = a02;
    float r1x = a01, r1y = m11, r1z = a12;
    float r2x = a02, r2y = a12, r2z = m22;
    float c0x = r0y * r1z - r0z * r1y, c0y = r0z * r1x - r0x * r1z, c0z = r0x * r1y - r0y * r1x;
    float c1x = r0y * r2z - r0z * r2y, c1y = r0z * r2x - r0x * r2z, c1z = r0x * r2y - r0y * r2x;
    float c2x = r1y * r2z - r1z * r2y, c2y = r1z * r2x - r1x * r2z, c2z = r1x * r2y - r1y * r2x;
    float n0 = c0x * c0x + c0y * c0y + c0z * c0z;
    float n1 = c1x * c1x + c1y * c1y + c1z * c1z;
    float n2 = c2x * c2x + c2y * c2y + c2z * c2z;
    float bx = c0x, by = c0y, bz = c0z, bnm = n0;
    if (n1 > bnm) { bx = c1x; by = c1y; bz = c1z; bnm = n1; }
    if (n2 > bnm) { bx = c2x; by = c2y; bz = c2z; bnm = n2; }
    if (bnm < 1e-30f) { vx = 1.0f; vy = 0.0f; vz = 0.0f; return; }
    float inv = rsqrtf(bnm);
    vx = bx * inv; vy = by * inv; vz = bz * inv;
}

__global__ void init_counter_kernel(unsigned* __restrict__ counter) {
    if (threadIdx.x == 0) *counter = 0u;
}

// 512 threads = 8 waves; lane l owns queries (base+l, base+l+64); wave w scans
// segment w (wave-uniform broadcast LDS reads). Cloud staged in two 32 KiB
// half-passes. Tree-merge of per-wave top-10s, then wave 0 does covariance +
// eigen. Last-finishing block reduces the loss (fence + atomic counter).
__global__ __launch_bounds__(TPB, 4) void knn_normals_fused(
    const float* __restrict__ pred, const float* __restrict__ gt,
    float* __restrict__ nbuf /* [BN][6] = pn.xyz, gn.xyz interleaved */,
    unsigned* __restrict__ counter, float* __restrict__ out) {
    __shared__ float4 pts[HALF];      // 32 KiB; aliased as merge keybuf later
    __shared__ float red[TPB];        // 2 KiB
    __shared__ int islast;

    const int b = blockIdx.y;
    const int cloud = blockIdx.z;
    const float* __restrict__ base = (cloud == 0 ? pred : gt) + b * 3 * NPTS;
    const int tid = threadIdx.x;
    const int lane = tid & 63;
    const int w = tid >> 6;           // wave id = segment id

    const int ptA = blockIdx.x * QPB + lane;
    const int ptB = ptA + 64;

    const float aAx = -2.0f * base[ptA], aAy = -2.0f * base[NPTS + ptA], aAz = -2.0f * base[2 * NPTS + ptA];
    const float aBx = -2.0f * base[ptB], aBy = -2.0f * base[NPTS + ptB], aBz = -2.0f * base[2 * NPTS + ptB];

    float kA[KNN], kB[KNN];
#pragma unroll
    for (int j = 0; j < KNN; ++j) { kA[j] = FLT_MAX; kB[j] = FLT_MAX; }

    const int poff = w * SEGC;        // wave-uniform
    for (int pass = 0; pass < 2; ++pass) {
        const int pb = pass * HALF;
#pragma unroll
        for (int i = tid; i < HALF; i += TPB) {
            float x = base[pb + i];
            float y = base[NPTS + pb + i];
            float z = base[2 * NPTS + pb + i];
            pts[i] = make_float4(x, y, z, fmaf(x, x, fmaf(y, y, z * z)));
        }
        __syncthreads();

        const unsigned gb = (unsigned)(pb + poff);
#pragma unroll 4
        for (int c = 0; c < SEGC; ++c) {
            float4 p = pts[poff + c];   // broadcast: same addr across the wave
            // shifted squared distance d' = |p|^2 - 2 p.q  (per-query constant
            // shift -|q|^2 preserves ordering); index packed into low 12 bits
            float dA = fmaf(p.z, aAz, fmaf(p.y, aAy, fmaf(p.x, aAx, p.w)));
            float dB = fmaf(p.z, aBz, fmaf(p.y, aBy, fmaf(p.x, aBx, p.w)));
            float keyA = __uint_as_float((__float_as_uint(dA) & 0xFFFFF000u) | (gb + c));
            float keyB = __uint_as_float((__float_as_uint(dB) & 0xFFFFF000u) | (gb + c));
            INSERT(kA, keyA);
            INSERT(kB, keyB);
        }
        __syncthreads();   // scan complete before restage / keybuf aliasing
    }

    // tree merge: 8 -> 4 -> 2 -> 1 (keybuf aliases dead stage buffer)
    float* keybuf = (float*)pts;
    for (int half = WAVES / 2; half >= 1; half >>= 1) {
        if (w >= half && w < 2 * half) {
            float* dst = keybuf + ((w - half) * 64 + lane) * KB_STRIDE;
#pragma unroll
            for (int j = 0; j < KNN; ++j) { dst[j] = kA[j]; dst[KNN + j] = kB[j]; }
        }
        __syncthreads();
        if (w < half) {
            const float* src = keybuf + (w * 64 + lane) * KB_STRIDE;
#pragma unroll
            for (int j = 0; j < KNN; ++j) {
                float sa = src[j], sb = src[KNN + j];
                INSERT(kA, sa);
                INSERT(kB, sb);
            }
        }
        __syncthreads();   // absorb-reads done before next round's dump-writes
    }

    if (w == 0) {
#pragma unroll
        for (int qi = 0; qi < 2; ++qi) {
            const float* kk = qi ? kB : kA;
            float sx = 0.f, sy = 0.f, sz = 0.f;
            float sxx = 0.f, sxy = 0.f, sxz = 0.f, syy = 0.f, syz = 0.f, szz = 0.f;
#pragma unroll
            for (int j = 0; j < KNN; ++j) {
                int idx = (int)(__float_as_uint(kk[j]) & 0xFFFu);
                float x = base[idx], y = base[NPTS + idx], z = base[2 * NPTS + idx];
                sx += x; sy += y; sz += z;
                sxx = fmaf(x, x, sxx); sxy = fmaf(x, y, sxy); sxz = fmaf(x, z, sxz);
                syy = fmaf(y, y, syy); syz = fmaf(y, z, syz); szz = fmaf(z, z, szz);
            }
            const float iK = 1.0f / KNN;
            float mx = sx * iK, my = sy * iK, mz = sz * iK;
            float cxx = sxx * iK - mx * mx, cxy = sxy * iK - mx * my, cxz = sxz * iK - mx * mz;
            float cyy = syy * iK - my * my, cyz = syz * iK - my * mz, czz = szz * iK - mz * mz;

            float vx, vy, vz;
            smallest_eigvec(cxx, cxy, cxz, cyy, cyz, czz, vx, vy, vz);

            const int pt = qi ? ptB : ptA;
            float* dst = nbuf + (size_t)(b * NPTS + pt) * 6 + 3 * cloud;
            dst[0] = vx; dst[1] = vy; dst[2] = vz;
        }
    }

    // completion protocol
    __threadfence();
    __syncthreads();
    if (tid == 0) {
        unsigned old = atomicAdd(counter, 1u);
        islast = (old == TOTAL_BLOCKS - 1) ? 1 : 0;
    }
    __syncthreads();

    if (islast) {
        __threadfence();   // acquire
        float acc = 0.f;
        for (int i = tid; i < BN; i += TPB) {
            const float* v = nbuf + (size_t)i * 6;
            float px = v[0], py = v[1], pz = v[2];
            float gx = v[3], gy = v[4], gz = v[5];
            float dot = px * gx + py * gy + pz * gz;
            float npn = sqrtf(px * px + py * py + pz * pz);
            float ngn = sqrtf(gx * gx + gy * gy + gz * gz);
            float denom = fmaxf(npn * ngn, 1e-8f);
            acc += 1.0f - fabsf(dot / denom);
        }
        red[tid] = acc;
        __syncthreads();
        for (int s = TPB / 2; s > 0; s >>= 1) {
            if (tid < s) red[tid] += red[tid + s];
            __syncthreads();
        }
        if (tid == 0) out[0] = red[0] * (1.0f / BN);
    }
}

extern "C" void kernel_launch(void* const* d_in, const int* in_sizes, int n_in,
                              void* d_out, int out_size, void* d_ws, size_t ws_size,
                              hipStream_t stream) {
    const float* pred = (const float*)d_in[0];
    const float* gt = (const float*)d_in[1];
    float* out = (float*)d_out;
    unsigned* counter = (unsigned*)d_ws;        // first 64 B slot
    float* nbuf = (float*)d_ws + 16;            // BN*6 floats = 768 KiB

    init_counter_kernel<<<1, 64, 0, stream>>>(counter);
    dim3 grid(GRIDX, BATCH, 2);                 // 32 x 8 x 2 = 512 blocks
    knn_normals_fused<<<grid, TPB, 0, stream>>>(pred, gt, nbuf, counter, out);
}